// Round 2
// baseline (538.678 us; speedup 1.0000x reference)
//
#include <hip/hip_runtime.h>
#include <stdint.h>

#define Bb 4
#define Tt 1024
#define Cc 768
#define Hh 12
#define Dd 64

typedef __attribute__((ext_vector_type(8))) short short8;
typedef __attribute__((ext_vector_type(4))) float f32x4;

__device__ inline unsigned short f2bf(float f) {
  union { float f; uint32_t u; } c; c.f = f;
  return (unsigned short)((c.u + 0x7FFFu + ((c.u >> 16) & 1u)) >> 16);
}

// ---------- fp32 -> bf16, same layout (x) ----------
__global__ void k_convert(const float* __restrict__ in, unsigned short* __restrict__ out, int n4) {
  int i = blockIdx.x * blockDim.x + threadIdx.x;
  if (i >= n4) return;
  float4 v = ((const float4*)in)[i];
  ushort4 o;
  o.x = f2bf(v.x); o.y = f2bf(v.y); o.z = f2bf(v.z); o.w = f2bf(v.w);
  ((ushort4*)out)[i] = o;
}

// ---------- W[K][N] fp32 -> WT[N][K] bf16, LDS-tiled (coalesced both sides) ----------
__global__ void k_transpose(const float* __restrict__ W, unsigned short* __restrict__ WT,
                            int K, int N) {
  __shared__ float tile[32][33];
  const int nb = N >> 5;
  const int bx = blockIdx.x % nb;   // n-tile
  const int by = blockIdx.x / nb;   // k-tile
  const int tx = threadIdx.x & 31, ty = threadIdx.x >> 5;  // 32 x 8
#pragma unroll
  for (int i = 0; i < 4; ++i)
    tile[ty + i * 8][tx] = W[(size_t)(by * 32 + ty + i * 8) * N + bx * 32 + tx];
  __syncthreads();
#pragma unroll
  for (int i = 0; i < 4; ++i)
    WT[(size_t)(bx * 32 + ty + i * 8) * K + by * 32 + tx] = f2bf(tile[tx][ty + i * 8]);
}

// ---------- Vb [bh][T][D] bf16 -> Vt [bh][D][T] bf16, LDS-tiled ----------
__global__ void k_vtrans(const unsigned short* __restrict__ Vb, unsigned short* __restrict__ Vt) {
  __shared__ unsigned short tile[32][34];
  const int bid = blockIdx.x;
  const int bh = bid >> 6;            // 48 heads
  const int ttile = (bid >> 1) & 31;  // 32 t-tiles
  const int dtile = bid & 1;          // 2 d-tiles
  const int tx = threadIdx.x & 31, ty = threadIdx.x >> 5;
  const unsigned short* src = Vb + ((size_t)bh * Tt + ttile * 32) * Dd + dtile * 32;
#pragma unroll
  for (int i = 0; i < 4; ++i)
    tile[ty + i * 8][tx] = src[(size_t)(ty + i * 8) * Dd + tx];
  __syncthreads();
  unsigned short* dst = Vt + ((size_t)bh * Dd + dtile * 32) * Tt + ttile * 32;
#pragma unroll
  for (int i = 0; i < 4; ++i)
    dst[(size_t)(ty + i * 8) * Tt + tx] = tile[tx][ty + i * 8];
}

// ---------- GEMM: C[M][N] = A[M][K] * BT[N][K]^T + bias ----------
// mode 0: scatter epilogue -> Qb/Kb/Vb [B,H,T,D] (all bf16, coalesced)
// mode 1: fp32 epilogue -> Y [M][N]
#define BM 128
#define BN 128
#define BK 32
#define LDK 40

__global__ __launch_bounds__(256, 3) void k_gemm(
    const unsigned short* __restrict__ A, const unsigned short* __restrict__ B,
    const float* __restrict__ bias, int M, int N, int K, int mode,
    unsigned short* __restrict__ Qb, unsigned short* __restrict__ Kb,
    unsigned short* __restrict__ Vb, float* __restrict__ Y)
{
  __shared__ __align__(16) unsigned short Al[BM][LDK];
  __shared__ __align__(16) unsigned short Bl[BN][LDK];
  const int nb = N / BN;
  const int m0 = (blockIdx.x / nb) * BM;
  const int n0 = (blockIdx.x % nb) * BN;
  const int tid = threadIdx.x;
  const int lane = tid & 63;
  const int w = tid >> 6;
  const int wm = (w & 1) * 64;
  const int wn = (w >> 1) * 64;
  const int l16 = lane & 15, q = lane >> 4;

  f32x4 acc[4][4];
#pragma unroll
  for (int i = 0; i < 4; ++i)
#pragma unroll
    for (int j = 0; j < 4; ++j)
#pragma unroll
      for (int e = 0; e < 4; ++e) acc[i][j][e] = 0.f;

  const int rrow = tid >> 1;       // 0..127
  const int kch = (tid & 1) * 16;  // 0 or 16 (bf16 units)

  for (int k0 = 0; k0 < K; k0 += BK) {
    int4 va0 = *(const int4*)(A + (size_t)(m0 + rrow) * K + k0 + kch);
    int4 va1 = *(const int4*)(A + (size_t)(m0 + rrow) * K + k0 + kch + 8);
    int4 vb0 = *(const int4*)(B + (size_t)(n0 + rrow) * K + k0 + kch);
    int4 vb1 = *(const int4*)(B + (size_t)(n0 + rrow) * K + k0 + kch + 8);
    __syncthreads();
    *(int4*)(&Al[rrow][kch])     = va0;
    *(int4*)(&Al[rrow][kch + 8]) = va1;
    *(int4*)(&Bl[rrow][kch])     = vb0;
    *(int4*)(&Bl[rrow][kch + 8]) = vb1;
    __syncthreads();
    short8 af[4], bfr[4];
#pragma unroll
    for (int t = 0; t < 4; ++t) {
      af[t]  = *(const short8*)(&Al[wm + t * 16 + l16][q * 8]);
      bfr[t] = *(const short8*)(&Bl[wn + t * 16 + l16][q * 8]);
    }
#pragma unroll
    for (int i = 0; i < 4; ++i)
#pragma unroll
      for (int j = 0; j < 4; ++j)
        acc[i][j] = __builtin_amdgcn_mfma_f32_16x16x32_bf16(af[i], bfr[j], acc[i][j], 0, 0, 0);
  }

#pragma unroll
  for (int i = 0; i < 4; ++i)
#pragma unroll
    for (int j = 0; j < 4; ++j) {
      int mg = m0 + wm + i * 16 + q * 4;
      int ng = n0 + wn + j * 16 + l16;
      float bv = bias[ng];
#pragma unroll
      for (int r = 0; r < 4; ++r) {
        float v = acc[i][j][r] + bv;
        int mr = mg + r;
        if (mode == 0) {
          int which = ng / Cc;
          int nn = ng - which * Cc;
          int hh = nn >> 6, d = nn & 63;
          int bb = mr >> 10, t = mr & 1023;
          int bh = bb * Hh + hh;
          unsigned short o = f2bf(v);
          unsigned short* dst = (which == 0) ? Qb : (which == 1) ? Kb : Vb;
          dst[((size_t)bh * Tt + t) * Dd + d] = o;
        } else {
          Y[(size_t)mr * N + ng] = v;
        }
      }
    }
}

// ---------- attention: 1 block = (b,h, 16 rows) x full 1024 cols ----------
// Swapped QK^T orientation: S = mfma(K_frag, Q_frag) => lane(l16) = query row,
// (q*4+r) = 4 consecutive key cols. bias/mask float4 loads, attn float4 stores.
// 16 rows/block halves the S accumulator footprint (64 regs) vs 32 rows ->
// target 3+ blocks/CU instead of 2 (round-1 counters: Occupancy 21%, latency-bound).
__global__ __launch_bounds__(256, 3) void k_attn(
    const unsigned short* __restrict__ Qb, const unsigned short* __restrict__ Kb,
    const unsigned short* __restrict__ Vt,
    const float* __restrict__ bias, const float* __restrict__ mask,
    float* __restrict__ attn, unsigned short* __restrict__ Ob)
{
  __shared__ __align__(16) unsigned short Pl[4][16][136];
  __shared__ float red[4][16];
  __shared__ float rowmax[16];
  __shared__ float rowinv[16];

  const int bid = blockIdx.x;
  const int bh = bid >> 6;
  const int tile = bid & 63;
  const int b = bh / Hh;
  const int h = bh - b * Hh;
  const int row0 = tile * 16;
  const int tid = threadIdx.x, lane = tid & 63, w = tid >> 6;
  const int l16 = lane & 15, q = lane >> 4;
  const int colw = w * 256;

  const unsigned short* Qp = Qb + ((size_t)bh * Tt + row0) * Dd;
  const unsigned short* Kp = Kb + (size_t)bh * Tt * Dd;
  const unsigned short* Vp = Vt + (size_t)bh * Dd * Tt;
  const float* bp = bias + ((size_t)bh * Tt + row0) * Tt;
  const float* mp = mask + ((size_t)b * Tt + row0) * Tt;
  float* ap = attn + ((size_t)bh * Tt + row0) * Tt;

  // Q fragments: lane l16 = query row, elements = k chunk
  short8 qf[2];
#pragma unroll
  for (int ks = 0; ks < 2; ++ks)
    qf[ks] = *(const short8*)(Qp + l16 * Dd + ks * 32 + q * 8);

  f32x4 S[16];
#pragma unroll
  for (int nt = 0; nt < 16; ++nt)
#pragma unroll
    for (int e = 0; e < 4; ++e) S[nt][e] = 0.f;

  // S^T = K Q^T over this wave's 256 columns
  __builtin_amdgcn_s_setprio(1);
#pragma unroll
  for (int nt = 0; nt < 16; ++nt) {
    int col = colw + nt * 16 + l16;
#pragma unroll
    for (int ks = 0; ks < 2; ++ks) {
      short8 kf = *(const short8*)(Kp + (size_t)col * Dd + ks * 32 + q * 8);
      S[nt] = __builtin_amdgcn_mfma_f32_16x16x32_bf16(kf, qf[ks], S[nt], 0, 0, 0);
    }
  }
  __builtin_amdgcn_s_setprio(0);

  // logits = S*scale + bias + mask  (float4 per nt)
  {
    const float* bR = bp + (size_t)l16 * Tt + colw + q * 4;
    const float* mR = mp + (size_t)l16 * Tt + colw + q * 4;
#pragma unroll
    for (int nt = 0; nt < 16; ++nt) {
      f32x4 bv = *(const f32x4*)(bR + nt * 16);
      f32x4 mv = *(const f32x4*)(mR + nt * 16);
      S[nt] = S[nt] * 0.125f + bv + mv;
    }
  }

  // row max: row = l16 lane-local; reduce across 4 q-groups then across waves
  {
    float m = S[0][0];
#pragma unroll
    for (int nt = 0; nt < 16; ++nt)
#pragma unroll
      for (int r = 0; r < 4; ++r) m = fmaxf(m, S[nt][r]);
    m = fmaxf(m, __shfl_xor(m, 16, 64));
    m = fmaxf(m, __shfl_xor(m, 32, 64));
    if (q == 0) red[w][l16] = m;
  }
  __syncthreads();
  if (tid < 16)
    rowmax[tid] = fmaxf(fmaxf(red[0][tid], red[1][tid]), fmaxf(red[2][tid], red[3][tid]));
  __syncthreads();

  // exp + row sum
  {
    float m = rowmax[l16];
    float s = 0.f;
#pragma unroll
    for (int nt = 0; nt < 16; ++nt)
#pragma unroll
      for (int r = 0; r < 4; ++r) {
        float p = __expf(S[nt][r] - m);
        S[nt][r] = p;
        s += p;
      }
    s += __shfl_xor(s, 16, 64);
    s += __shfl_xor(s, 32, 64);
    if (q == 0) red[w][l16] = s;
  }
  __syncthreads();
  if (tid < 16)
    rowinv[tid] = 1.0f / (red[0][tid] + red[1][tid] + red[2][tid] + red[3][tid]);
  __syncthreads();

  // normalize, write attn (float4), stage P (ushort4) per 128-col half, then P·V
  f32x4 O[4];
#pragma unroll
  for (int dt = 0; dt < 4; ++dt)
#pragma unroll
    for (int e = 0; e < 4; ++e) O[dt][e] = 0.f;

  const float inv = rowinv[l16];
  for (int half = 0; half < 2; ++half) {
    __syncthreads();
    {
      float* apR = ap + (size_t)l16 * Tt + colw + q * 4;
#pragma unroll
      for (int nn = 0; nn < 8; ++nn) {
        int nt = half * 8 + nn;
        f32x4 p = S[nt] * inv;
        *(f32x4*)(apR + nt * 16) = p;
        ushort4 pb;
        pb.x = f2bf(p[0]); pb.y = f2bf(p[1]); pb.z = f2bf(p[2]); pb.w = f2bf(p[3]);
        *(ushort4*)(&Pl[w][l16][nn * 16 + q * 4]) = pb;
      }
    }
    __syncthreads();
    __builtin_amdgcn_s_setprio(1);
#pragma unroll
    for (int kt = 0; kt < 4; ++kt) {
      short8 pf = *(const short8*)(&Pl[w][l16][kt * 32 + q * 8]);
#pragma unroll
      for (int dt = 0; dt < 4; ++dt) {
        short8 vf = *(const short8*)(Vp + (size_t)(dt * 16 + l16) * Tt
                                     + colw + half * 128 + kt * 32 + q * 8);
        O[dt] = __builtin_amdgcn_mfma_f32_16x16x32_bf16(pf, vf, O[dt], 0, 0, 0);
      }
    }
    __builtin_amdgcn_s_setprio(0);
  }

  // cross-wave O reduction through LDS (reuse Pl: need 16 KB, have 17.4 KB)
  __syncthreads();
  float* Op = (float*)&Pl[0][0][0] + w * 1024;
#pragma unroll
  for (int dt = 0; dt < 4; ++dt)
#pragma unroll
    for (int r = 0; r < 4; ++r) {
      int row = q * 4 + r;
      int d = dt * 16 + l16;
      Op[row * 64 + d] = O[dt][r];
    }
  __syncthreads();
  float* base = (float*)&Pl[0][0][0];
  for (int e = tid; e < 1024; e += 256) {
    float v = base[e] + base[1024 + e] + base[2048 + e] + base[3072 + e];
    int row = e >> 6, d = e & 63;
    Ob[((size_t)(b * Tt + row0 + row)) * Cc + h * Dd + d] = f2bf(v);
  }
}

extern "C" void kernel_launch(void* const* d_in, const int* in_sizes, int n_in,
                              void* d_out, int out_size, void* d_ws, size_t ws_size,
                              hipStream_t stream) {
  const float* x     = (const float*)d_in[0];
  const float* maskl = (const float*)d_in[1];
  const float* bias  = (const float*)d_in[2];
  const float* Wqkv  = (const float*)d_in[3];
  const float* bqkv  = (const float*)d_in[4];
  const float* Wproj = (const float*)d_in[5];
  const float* bproj = (const float*)d_in[6];
  float* y    = (float*)d_out;
  float* attn = y + (size_t)Bb * Tt * Cc;

  char* ws = (char*)d_ws;
  unsigned short* xb     = (unsigned short*)(ws);             // 6,291,456 B
  unsigned short* WqkvT  = (unsigned short*)(ws + 6291456);   // 3,538,944 B
  unsigned short* WprojT = (unsigned short*)(ws + 9830400);   // 1,179,648 B
  unsigned short* Qb     = (unsigned short*)(ws + 11010048);  // 6,291,456 B
  unsigned short* Kb     = (unsigned short*)(ws + 17301504);  // 6,291,456 B
  unsigned short* Vt     = (unsigned short*)(ws + 23592960);  // 6,291,456 B
  unsigned short* Ob     = (unsigned short*)(ws + 29884416);  // 6,291,456 B -> 36,175,872 total
  // Vb (row-major V) shares the Ob region: k_vtrans consumes it before k_attn writes Ob.
  unsigned short* Vb     = Ob;

  k_convert<<<3072, 256, 0, stream>>>(x, xb, 786432);
  k_transpose<<<1728, 256, 0, stream>>>(Wqkv, WqkvT, 768, 2304);
  k_transpose<<<576, 256, 0, stream>>>(Wproj, WprojT, 768, 768);
  k_gemm<<<576, 256, 0, stream>>>(xb, WqkvT, bqkv, 4096, 2304, 768, 0,
                                  Qb, Kb, Vb, nullptr);
  k_vtrans<<<3072, 256, 0, stream>>>(Vb, Vt);
  k_attn<<<3072, 256, 0, stream>>>(Qb, Kb, Vt, bias, maskl, attn, Ob);
  k_gemm<<<192, 256, 0, stream>>>(Ob, WprojT, bproj, 4096, 768, 768, 1,
                                  nullptr, nullptr, nullptr, y);
}